// Round 7
// baseline (5094.960 us; speedup 1.0000x reference)
//
#include <hip/hip_runtime.h>
#include <hip/hip_cooperative_groups.h>

namespace cg = cooperative_groups;

#define IDX_BITS 20
#define IDX_MASK ((1u << IDX_BITS) - 1)
#define NTHREADS 1024
#define MAX_GRID 512
#define T1 49152          // grid-sync tier while alive > T1
#define TB2 64            // tier-2 block count (spin barrier)
#define T2 3072           // tier-2 while alive > T2; below: single-block tier-3
#define GRID_ROUND_CAP 24
#define MAX_ROUNDS 8000
#define SC_CAP 1024
#define SV_CAP 4096

typedef unsigned long long u64;

// All edges are intra-segment, so the per-edge comparison key drops seg:
// key = (~float_bits(hier) << 20) | v ; smaller = earlier in processing order.
__device__ __forceinline__ u64 pack_key(float h, int v) {
  return ((u64)(~__float_as_uint(h)) << IDX_BITS) | (unsigned)v;
}

struct Ctx {
  const int* __restrict__ neighs;
  const float* __restrict__ hier;
  const int* __restrict__ row_splits;
  int V, K, nseg;
  u64* assign;       // [V] min grabber key; ~0 = alive; == own key -> decided centre
  int* tag;          // [V] "blocked at round r" tags (plain racy stores of r)
  int* listA;        // [V] frontier ping
  int* listB;        // [V] frontier pong
  u64* centre_key;   // [V] full key incl. seg (for global ranking)
  int* centre_v;     // [V]
  int* rank_of;      // [V]
  int* cnt;          // [0,1] survivor counters (parity), [2] nC, [3] xbar, [4] claim, [8+s] seg
  int* out_sel;
  int* out_rs;
  int* out_gg;
};

// Monotonic arrive-counter barrier for the TB2 group. threadfence on both
// sides (L1 invalidate) preserves the cross-round freshness argument.
__device__ __forceinline__ void xbar(int* bar, int target) {
  __syncthreads();
  __threadfence();
  if (threadIdx.x == 0) {
    __hip_atomic_fetch_add(bar, 1, __ATOMIC_RELEASE, __HIP_MEMORY_SCOPE_AGENT);
    while (__hip_atomic_load(bar, __ATOMIC_ACQUIRE, __HIP_MEMORY_SCOPE_AGENT) < target)
      __builtin_amdgcn_s_sleep(2);
  }
  __syncthreads();
  __threadfence();
}

__global__ void __launch_bounds__(NTHREADS, 8) cluster_kernel(Ctx c) {
  cg::grid_group grid = cg::this_grid();
  const int tid = blockIdx.x * blockDim.x + threadIdx.x;
  const int nthr = gridDim.x * blockDim.x;
  const int V = c.V, K = c.K, nq = K >> 2;

  __shared__ int sc_cnt, sv_cnt, sc_base, sv_base, claim_sh;
  __shared__ int seg_hist[8];
  __shared__ int sc_list[SC_CAP];
  __shared__ int sv_list[SV_CAP];
  __shared__ u64 shp[NTHREADS];

  auto record_direct = [&](int v, u64 pv) {   // SC_CAP overflow fallback (rare)
    int slot = atomicAdd(&c.cnt[2], 1);
    int seg = 0;
    for (int t = 1; t < c.nseg; ++t) seg += (v >= c.row_splits[t]);
    c.centre_v[slot] = v;
    c.centre_key[slot] = ((u64)seg << 52) | pv;
    atomicAdd(&c.cnt[8 + seg], 1);
  };

  // Vertex-per-thread phase B: iterations independent -> deep MLP pipelining.
  auto phaseB = [&](const int* rl, int an, int r, int start, int stride) {
    for (int i = start; i < an; i += stride) {
      int u = rl ? rl[i] : i;
      u64 pu = pack_key(c.hier[u], u);
      if (c.assign[u] <= pu) continue;
      const int* rowp = c.neighs + (size_t)u * K;
      const int4* row4 = (const int4*)rowp;     // rows are 384B -> 16B aligned
      for (int q = 0; q < nq; ++q) {
        int4 w = row4[q];
        if (pack_key(c.hier[w.x], w.x) > pu) c.tag[w.x] = r;
        if (pack_key(c.hier[w.y], w.y) > pu) c.tag[w.y] = r;
        if (pack_key(c.hier[w.z], w.z) > pu) c.tag[w.z] = r;
        if (pack_key(c.hier[w.w], w.w) > pu) c.tag[w.w] = r;
      }
      for (int j = nq << 2; j < K; ++j) {
        int w = rowp[j];
        if (pack_key(c.hier[w], w) > pu) c.tag[w] = r;
      }
    }
  };
  // Vertex-per-thread phase C. Unguarded atomicMin: too-large values are
  // inert for every consumer (proved r5/6); grabs of earlier neighbours write
  // junk > target's own key which all tests ignore.
  auto phaseC = [&](const int* rl, int* wl, int* survc, int an, int r,
                    int start, int stride) {
    for (int i = start; i < an; i += stride) {
      int u = rl ? rl[i] : i;
      u64 pu = pack_key(c.hier[u], u);
      if (c.assign[u] <= pu) continue;
      if (c.tag[u] != r) {
        const int* rowp = c.neighs + (size_t)u * K;
        const int4* row4 = (const int4*)rowp;
        for (int q = 0; q < nq; ++q) {
          int4 w = row4[q];
          atomicMin(&c.assign[w.x], pu);
          atomicMin(&c.assign[w.y], pu);
          atomicMin(&c.assign[w.z], pu);
          atomicMin(&c.assign[w.w], pu);
        }
        for (int j = nq << 2; j < K; ++j) atomicMin(&c.assign[rowp[j]], pu);
        int s = atomicAdd(&sc_cnt, 1);
        if (s < SC_CAP) sc_list[s] = u; else record_direct(u, pu);
      } else {
        // fresh agent-scope re-check trims stale listings of same-round grabs
        u64 y = __hip_atomic_load(&c.assign[u], __ATOMIC_RELAXED, __HIP_MEMORY_SCOPE_AGENT);
        if (y > pu) {
          int s = atomicAdd(&sv_cnt, 1);
          if (s < SV_CAP) sv_list[s] = u;
          else { int g = atomicAdd(survc, 1); wl[g] = u; }
        }
      }
    }
  };
  // Block-aggregated flush: ONE global atomicAdd for slots + <=nseg for counts.
  auto flush_block = [&](int* wl, int* survc) {
    __syncthreads();
    int nsc = min(sc_cnt, SC_CAP), nsv = min(sv_cnt, SV_CAP);
    if (threadIdx.x == 0 && nsc) sc_base = atomicAdd(&c.cnt[2], nsc);
    if (threadIdx.x == 0 && nsv) sv_base = atomicAdd(survc, nsv);
    if (threadIdx.x < 8) seg_hist[threadIdx.x] = 0;
    __syncthreads();
    for (int i = threadIdx.x; i < nsv; i += blockDim.x) wl[sv_base + i] = sv_list[i];
    for (int i = threadIdx.x; i < nsc; i += blockDim.x) {
      int v = sc_list[i];
      int seg = 0;
      for (int t = 1; t < c.nseg; ++t) seg += (v >= c.row_splits[t]);
      c.centre_v[sc_base + i] = v;
      c.centre_key[sc_base + i] = ((u64)seg << 52) | pack_key(c.hier[v], v);
      atomicAdd(&seg_hist[seg], 1);
    }
    __syncthreads();
    if (threadIdx.x < c.nseg) {
      int h = seg_hist[threadIdx.x];
      if (h) atomicAdd(&c.cnt[8 + threadIdx.x], h);
    }
    __syncthreads();
    if (threadIdx.x == 0) { sc_cnt = 0; sv_cnt = 0; }
  };

  if (threadIdx.x == 0) { sc_cnt = 0; sv_cnt = 0; }

  // ================= tier 1: grid-sync rounds (huge frontiers) =================
  int aliveN = V, r = 0;
  while (true) {
    const int* rl = (r & 1) ? c.listA : c.listB;
    int* wl = (r & 1) ? c.listB : c.listA;
    if (tid == 0) c.cnt[(r + 1) & 1] = 0;      // 2 syncs since last read of slot
    phaseB(r ? rl : nullptr, aliveN, r, tid, nthr);
    __threadfence();
    grid.sync();
    phaseC(r ? rl : nullptr, wl, &c.cnt[(r + 1) & 1], aliveN, r, tid, nthr);
    flush_block(wl, &c.cnt[(r + 1) & 1]);
    __threadfence();
    grid.sync();
    aliveN = c.cnt[(r + 1) & 1];
    ++r;
    if (aliveN == 0 || aliveN <= T1 || r >= GRID_ROUND_CAP) break;
  }

  // ================= tiers 2+3 =================
  if (aliveN > 0) {
    if (threadIdx.x == 0) claim_sh = atomicAdd(&c.cnt[4], 1);
    __syncthreads();
    const int trank = claim_sh;
    int an = aliveN, tr = r;

    // tier 2: TB2 blocks, spin barrier, mid frontiers
    if (trank < TB2 && an > T2) {
      const int startT = trank * NTHREADS + threadIdx.x;
      const int strideT = TB2 * NTHREADS;
      int ep = 0;
      while (true) {
        const int* rl = (tr & 1) ? c.listA : c.listB;
        int* wl = (tr & 1) ? c.listB : c.listA;
        if (trank == 0 && threadIdx.x == 0) c.cnt[(tr + 1) & 1] = 0;
        phaseB(rl, an, tr, startT, strideT);
        xbar(&c.cnt[3], TB2 * (++ep));
        phaseC(rl, wl, &c.cnt[(tr + 1) & 1], an, tr, startT, strideT);
        flush_block(wl, &c.cnt[(tr + 1) & 1]);
        xbar(&c.cnt[3], TB2 * (++ep));
        an = c.cnt[(tr + 1) & 1];
        ++tr;
        if (an == 0 || an <= T2 || tr >= MAX_ROUNDS) break;
      }
    }

    // tier 3: single block, ~0.2us barriers, runs the long low-work tail.
    // Round ids stay globally monotonic -> tag semantics unchanged.
    if (trank == 0) {
      while (an > 0 && tr < MAX_ROUNDS) {
        const int* rl = (tr & 1) ? c.listA : c.listB;
        int* wl = (tr & 1) ? c.listB : c.listA;
        if (threadIdx.x == 0) c.cnt[(tr + 1) & 1] = 0;
        phaseB(rl, an, tr, threadIdx.x, NTHREADS);
        __threadfence(); __syncthreads();      // L1 inv: see own block's L2 atomics
        phaseC(rl, wl, &c.cnt[(tr + 1) & 1], an, tr, threadIdx.x, NTHREADS);
        flush_block(wl, &c.cnt[(tr + 1) & 1]);
        __threadfence(); __syncthreads();
        an = c.cnt[(tr + 1) & 1];
        ++tr;
      }
    }
  }
  __threadfence();
  grid.sync();

  // ================= centre ranks: O(nC^2) LDS-tiled counting =================
  int nC = c.cnt[2];
  if ((long long)blockIdx.x * blockDim.x < (long long)nC) {
    bool have = tid < nC;
    u64 mykey = have ? c.centre_key[tid] : 0;
    int myv = have ? c.centre_v[tid] : 0;
    int myrank = 0;
    for (int cs = 0; cs < nC; cs += NTHREADS) {
      int j = cs + threadIdx.x;
      shp[threadIdx.x] = (j < nC) ? c.centre_key[j] : ~0ull;
      __syncthreads();
      int lim = min(NTHREADS, nC - cs);
      for (int t = 0; t < lim; ++t) myrank += (shp[t] < mykey) ? 1 : 0;
      __syncthreads();
    }
    if (have) {
      c.out_sel[myrank] = myv;     // rank among centre keys == cumsum position
      c.rank_of[myv] = myrank;
    }
  }
  if (tid == 0) {
    int run = 0;
    c.out_rs[0] = 0;
    for (int s = 0; s < c.nseg; ++s) { run += c.cnt[8 + s]; c.out_rs[s + 1] = run; }
  }
  __threadfence();
  grid.sync();

  // ================= ggather =================
  for (int v = tid; v < V; v += nthr) {
    u64 y = c.assign[v];
    u64 pv = pack_key(c.hier[v], v);
    int ctr = (y < pv) ? (int)(y & IDX_MASK) : v;   // y==pv -> centre -> self
    c.out_gg[v] = c.rank_of[ctr];
  }
}

extern "C" void kernel_launch(void* const* d_in, const int* in_sizes, int n_in,
                              void* d_out, int out_size, void* d_ws, size_t ws_size,
                              hipStream_t stream) {
  Ctx c;
  c.neighs = (const int*)d_in[0];
  c.hier = (const float*)d_in[1];
  c.row_splits = (const int*)d_in[2];
  c.V = in_sizes[1];
  c.K = in_sizes[0] / c.V;
  c.nseg = in_sizes[2] - 1;

  char* pm = (char*)d_ws;
  const size_t V = (size_t)c.V;
  c.assign = (u64*)pm;        pm += V * 8;
  c.tag = (int*)pm;           pm += V * 4;
  size_t ff_bytes = V * 12;   // assign -> ~0 (alive), tag -> -1
  c.listA = (int*)pm;         pm += V * 4;
  c.listB = (int*)pm;         pm += V * 4;
  c.centre_key = (u64*)pm;    pm += V * 8;
  c.centre_v = (int*)pm;      pm += V * 4;
  c.rank_of = (int*)pm;       pm += V * 4;
  c.cnt = (int*)pm;           pm += 64 * 4;

  int* out = (int*)d_out;
  c.out_sel = out;
  c.out_rs = out + c.V;
  c.out_gg = out + c.V + c.nseg + 1;

  hipMemsetAsync(d_ws, 0xFF, ff_bytes, stream);
  hipMemsetAsync((void*)c.cnt, 0, 64 * 4, stream);
  hipMemsetAsync((void*)c.out_sel, 0xFF, V * 4, stream);

  int dev = 0, nCU = 0, maxB = 0;
  hipGetDevice(&dev);
  hipDeviceGetAttribute(&nCU, hipDeviceAttributeMultiprocessorCount, dev);
  hipOccupancyMaxActiveBlocksPerMultiprocessor(&maxB, cluster_kernel, NTHREADS, 0);
  if (nCU <= 0) nCU = 256;
  if (maxB <= 0) maxB = 1;
  int grid = nCU * maxB;
  if (grid > MAX_GRID) grid = MAX_GRID;

  void* args[] = { &c };
  hipLaunchCooperativeKernel((void*)cluster_kernel, dim3(grid), dim3(NTHREADS),
                             args, 0, stream);
}

// Round 8
// 2060.332 us; speedup vs baseline: 2.4729x; 2.4729x over previous
//
#include <hip/hip_runtime.h>
#include <hip/hip_cooperative_groups.h>

namespace cg = cooperative_groups;

#define IDX_BITS 20
#define IDX_MASK ((1u << IDX_BITS) - 1)
#define NTHREADS 1024
#define MAX_GRID 512
#define T1 49152          // grid-sync tier while alive > T1
#define TB2 16            // tier-2 block count (spin barrier)
#define T2 1536           // tier-2 while alive > T2; below: single-block tier-3
#define GRID_ROUND_CAP 16
#define MAX_ROUNDS 8000
#define SC_CAP 1024
#define SV_CAP 4096

typedef unsigned long long u64;

// All edges are intra-segment, so the per-edge comparison key drops seg:
// key = (~float_bits(hier) << 20) | v ; smaller = earlier in processing order.
__device__ __forceinline__ u64 pack_key(float h, int v) {
  return ((u64)(~__float_as_uint(h)) << IDX_BITS) | (unsigned)v;
}

struct Ctx {
  const int* __restrict__ neighs;
  const float* __restrict__ hier;
  const int* __restrict__ row_splits;
  int V, K, nseg;
  u64* assign;       // [V] min grabber key; ~0 = alive; == own key -> decided centre
  int* tag;          // [V] "blocked at round r" tags (plain racy stores of r)
  int* listA;        // [V] frontier ping
  int* listB;        // [V] frontier pong
  u64* centre_key;   // [V] full key incl. seg (for global ranking)
  int* centre_v;     // [V]
  int* rank_of;      // [V]
  int* cnt;          // [0,1] survivor counters (parity), [2] nC, [3] xbar, [4] claim, [8+s] seg
  int* out_sel;
  int* out_rs;
  int* out_gg;
};

// Monotonic arrive-counter barrier for the TB2 group. threadfence on both
// sides (L1 invalidate) preserves the cross-round freshness argument.
__device__ __forceinline__ void xbar(int* bar, int target) {
  __syncthreads();
  __threadfence();
  if (threadIdx.x == 0) {
    __hip_atomic_fetch_add(bar, 1, __ATOMIC_RELEASE, __HIP_MEMORY_SCOPE_AGENT);
    while (__hip_atomic_load(bar, __ATOMIC_ACQUIRE, __HIP_MEMORY_SCOPE_AGENT) < target)
      __builtin_amdgcn_s_sleep(2);
  }
  __syncthreads();
  __threadfence();
}

__global__ void __launch_bounds__(NTHREADS, 8) cluster_kernel(Ctx c) {
  cg::grid_group grid = cg::this_grid();
  const int tid = blockIdx.x * blockDim.x + threadIdx.x;
  const int nthr = gridDim.x * blockDim.x;
  const int V = c.V, K = c.K;
  const int ql = threadIdx.x & 15;          // lane within quarter-wave
  const int bq = threadIdx.x >> 4;          // quarter id within block (64)
  const int NBQ = NTHREADS >> 4;

  __shared__ int sc_cnt, sv_cnt, sc_base, sv_base, claim_sh;
  __shared__ int seg_hist[8];
  __shared__ int sc_list[SC_CAP];
  __shared__ int sv_list[SV_CAP];
  __shared__ u64 shp[NTHREADS];

  auto record_direct = [&](int v, u64 pv) {   // SC_CAP overflow fallback (rare)
    int slot = atomicAdd(&c.cnt[2], 1);
    int seg = 0;
    for (int t = 1; t < c.nseg; ++t) seg += (v >= c.row_splits[t]);
    c.centre_v[slot] = v;
    c.centre_key[slot] = ((u64)seg << 52) | pv;
    atomicAdd(&c.cnt[8 + seg], 1);
  };

  // Quarter-wave (16 lanes) per vertex: row reads stay 64B-coalesced while
  // 4 independent vertices/wave give 4x memory-level parallelism (r7 lesson:
  // thread-per-vertex loses coalescing, full-wave loses MLP).
  auto phaseB = [&](const int* rl, int an, int r, int qstart, int qstride) {
    if (K == 96) {
      for (int i = qstart; i < an; i += qstride) {
        int u = rl ? rl[i] : i;
        u64 pu = pack_key(c.hier[u], u);
        if (c.assign[u] <= pu) continue;
        const int* row = c.neighs + (size_t)u * 96;
        int w[6];
#pragma unroll
        for (int t = 0; t < 6; ++t) w[t] = row[ql + 16 * t];
#pragma unroll
        for (int t = 0; t < 6; ++t)
          if (pack_key(c.hier[w[t]], w[t]) > pu) c.tag[w[t]] = r;
      }
    } else {
      for (int i = qstart; i < an; i += qstride) {
        int u = rl ? rl[i] : i;
        u64 pu = pack_key(c.hier[u], u);
        if (c.assign[u] <= pu) continue;
        const int* row = c.neighs + (size_t)u * K;
        for (int j = ql; j < K; j += 16) {
          int w = row[j];
          if (pack_key(c.hier[w], w) > pu) c.tag[w] = r;
        }
      }
    }
  };
  // Unguarded atomicMin grabs: too-large values are inert for every consumer.
  auto phaseC = [&](const int* rl, int* wl, int* survc, int an, int r,
                    int qstart, int qstride) {
    for (int i = qstart; i < an; i += qstride) {
      int u = rl ? rl[i] : i;
      u64 pu = pack_key(c.hier[u], u);
      if (c.assign[u] <= pu) continue;
      if (c.tag[u] != r) {
        const int* row = c.neighs + (size_t)u * K;
        if (K == 96) {
          int w[6];
#pragma unroll
          for (int t = 0; t < 6; ++t) w[t] = row[ql + 16 * t];
#pragma unroll
          for (int t = 0; t < 6; ++t) atomicMin(&c.assign[w[t]], pu);
        } else {
          for (int j = ql; j < K; j += 16) atomicMin(&c.assign[row[j]], pu);
        }
        if (ql == 0) {
          int s = atomicAdd(&sc_cnt, 1);
          if (s < SC_CAP) sc_list[s] = u; else record_direct(u, pu);
        }
      } else if (ql == 0) {
        // fresh agent-scope re-check trims stale listings of same-round grabs
        u64 y = __hip_atomic_load(&c.assign[u], __ATOMIC_RELAXED, __HIP_MEMORY_SCOPE_AGENT);
        if (y > pu) {
          int s = atomicAdd(&sv_cnt, 1);
          if (s < SV_CAP) sv_list[s] = u;
          else { int g = atomicAdd(survc, 1); wl[g] = u; }
        }
      }
    }
  };
  // Block-aggregated flush: ONE global atomicAdd for slots + <=nseg for counts.
  auto flush_block = [&](int* wl, int* survc) {
    __syncthreads();
    int nsc = min(sc_cnt, SC_CAP), nsv = min(sv_cnt, SV_CAP);
    if (threadIdx.x == 0 && nsc) sc_base = atomicAdd(&c.cnt[2], nsc);
    if (threadIdx.x == 0 && nsv) sv_base = atomicAdd(survc, nsv);
    if (threadIdx.x < 8) seg_hist[threadIdx.x] = 0;
    __syncthreads();
    for (int i = threadIdx.x; i < nsv; i += blockDim.x) wl[sv_base + i] = sv_list[i];
    for (int i = threadIdx.x; i < nsc; i += blockDim.x) {
      int v = sc_list[i];
      int seg = 0;
      for (int t = 1; t < c.nseg; ++t) seg += (v >= c.row_splits[t]);
      c.centre_v[sc_base + i] = v;
      c.centre_key[sc_base + i] = ((u64)seg << 52) | pack_key(c.hier[v], v);
      atomicAdd(&seg_hist[seg], 1);
    }
    __syncthreads();
    if (threadIdx.x < c.nseg) {
      int h = seg_hist[threadIdx.x];
      if (h) atomicAdd(&c.cnt[8 + threadIdx.x], h);
    }
    __syncthreads();
    if (threadIdx.x == 0) { sc_cnt = 0; sv_cnt = 0; }
  };

  if (threadIdx.x == 0) { sc_cnt = 0; sv_cnt = 0; }

  // ================= tier 1: grid-sync rounds (huge frontiers) =================
  int aliveN = V, r = 0;
  {
    const int qg = tid >> 4, nq = nthr >> 4;
    while (true) {
      const int* rl = (r & 1) ? c.listA : c.listB;
      int* wl = (r & 1) ? c.listB : c.listA;
      if (tid == 0) c.cnt[(r + 1) & 1] = 0;    // 2 syncs since last read of slot
      phaseB(r ? rl : nullptr, aliveN, r, qg, nq);
      __threadfence();
      grid.sync();
      phaseC(r ? rl : nullptr, wl, &c.cnt[(r + 1) & 1], aliveN, r, qg, nq);
      flush_block(wl, &c.cnt[(r + 1) & 1]);
      __threadfence();
      grid.sync();
      aliveN = c.cnt[(r + 1) & 1];
      ++r;
      if (aliveN == 0 || aliveN <= T1 || r >= GRID_ROUND_CAP) break;
    }
  }

  // ================= tiers 2+3 =================
  if (aliveN > 0) {
    if (threadIdx.x == 0) claim_sh = atomicAdd(&c.cnt[4], 1);
    __syncthreads();
    const int trank = claim_sh;
    int an = aliveN, tr = r;

    // tier 2: TB2 blocks, spin barrier, mid frontiers
    if (trank < TB2 && an > T2) {
      const int qstart = trank * NBQ + bq;
      const int qstride = TB2 * NBQ;
      int ep = 0;
      while (true) {
        const int* rl = (tr & 1) ? c.listA : c.listB;
        int* wl = (tr & 1) ? c.listB : c.listA;
        if (trank == 0 && threadIdx.x == 0) c.cnt[(tr + 1) & 1] = 0;
        phaseB(rl, an, tr, qstart, qstride);
        xbar(&c.cnt[3], TB2 * (++ep));
        phaseC(rl, wl, &c.cnt[(tr + 1) & 1], an, tr, qstart, qstride);
        flush_block(wl, &c.cnt[(tr + 1) & 1]);
        xbar(&c.cnt[3], TB2 * (++ep));
        an = c.cnt[(tr + 1) & 1];
        ++tr;
        if (an == 0 || an <= T2 || tr >= MAX_ROUNDS) break;
      }
    }

    // tier 3: single block, ~0.2us barriers, runs the long low-work tail.
    // Round ids stay globally monotonic -> tag semantics unchanged.
    if (trank == 0) {
      while (an > 0 && tr < MAX_ROUNDS) {
        const int* rl = (tr & 1) ? c.listA : c.listB;
        int* wl = (tr & 1) ? c.listB : c.listA;
        if (threadIdx.x == 0) c.cnt[(tr + 1) & 1] = 0;
        phaseB(rl, an, tr, bq, NBQ);
        __threadfence(); __syncthreads();      // L1 inv: see own block's L2 atomics
        phaseC(rl, wl, &c.cnt[(tr + 1) & 1], an, tr, bq, NBQ);
        flush_block(wl, &c.cnt[(tr + 1) & 1]);
        __threadfence(); __syncthreads();
        an = c.cnt[(tr + 1) & 1];
        ++tr;
      }
    }
  }
  __threadfence();
  grid.sync();

  // ================= centre ranks: O(nC^2) LDS-tiled counting =================
  int nC = c.cnt[2];
  if ((long long)blockIdx.x * blockDim.x < (long long)nC) {
    bool have = tid < nC;
    u64 mykey = have ? c.centre_key[tid] : 0;
    int myv = have ? c.centre_v[tid] : 0;
    int myrank = 0;
    for (int cs = 0; cs < nC; cs += NTHREADS) {
      int j = cs + threadIdx.x;
      shp[threadIdx.x] = (j < nC) ? c.centre_key[j] : ~0ull;
      __syncthreads();
      int lim = min(NTHREADS, nC - cs);
      for (int t = 0; t < lim; ++t) myrank += (shp[t] < mykey) ? 1 : 0;
      __syncthreads();
    }
    if (have) {
      c.out_sel[myrank] = myv;     // rank among centre keys == cumsum position
      c.rank_of[myv] = myrank;
    }
  }
  if (tid == 0) {
    int run = 0;
    c.out_rs[0] = 0;
    for (int s = 0; s < c.nseg; ++s) { run += c.cnt[8 + s]; c.out_rs[s + 1] = run; }
  }
  __threadfence();
  grid.sync();

  // ================= ggather =================
  for (int v = tid; v < V; v += nthr) {
    u64 y = c.assign[v];
    u64 pv = pack_key(c.hier[v], v);
    int ctr = (y < pv) ? (int)(y & IDX_MASK) : v;   // y==pv -> centre -> self
    c.out_gg[v] = c.rank_of[ctr];
  }
}

extern "C" void kernel_launch(void* const* d_in, const int* in_sizes, int n_in,
                              void* d_out, int out_size, void* d_ws, size_t ws_size,
                              hipStream_t stream) {
  Ctx c;
  c.neighs = (const int*)d_in[0];
  c.hier = (const float*)d_in[1];
  c.row_splits = (const int*)d_in[2];
  c.V = in_sizes[1];
  c.K = in_sizes[0] / c.V;
  c.nseg = in_sizes[2] - 1;

  char* pm = (char*)d_ws;
  const size_t V = (size_t)c.V;
  c.assign = (u64*)pm;        pm += V * 8;
  c.tag = (int*)pm;           pm += V * 4;
  size_t ff_bytes = V * 12;   // assign -> ~0 (alive), tag -> -1
  c.listA = (int*)pm;         pm += V * 4;
  c.listB = (int*)pm;         pm += V * 4;
  c.centre_key = (u64*)pm;    pm += V * 8;
  c.centre_v = (int*)pm;      pm += V * 4;
  c.rank_of = (int*)pm;       pm += V * 4;
  c.cnt = (int*)pm;           pm += 64 * 4;

  int* out = (int*)d_out;
  c.out_sel = out;
  c.out_rs = out + c.V;
  c.out_gg = out + c.V + c.nseg + 1;

  hipMemsetAsync(d_ws, 0xFF, ff_bytes, stream);
  hipMemsetAsync((void*)c.cnt, 0, 64 * 4, stream);
  hipMemsetAsync((void*)c.out_sel, 0xFF, V * 4, stream);

  int dev = 0, nCU = 0, maxB = 0;
  hipGetDevice(&dev);
  hipDeviceGetAttribute(&nCU, hipDeviceAttributeMultiprocessorCount, dev);
  hipOccupancyMaxActiveBlocksPerMultiprocessor(&maxB, cluster_kernel, NTHREADS, 0);
  if (nCU <= 0) nCU = 256;
  if (maxB <= 0) maxB = 1;
  int grid = nCU * maxB;
  if (grid > MAX_GRID) grid = MAX_GRID;

  void* args[] = { &c };
  hipLaunchCooperativeKernel((void*)cluster_kernel, dim3(grid), dim3(NTHREADS),
                             args, 0, stream);
}